// Round 4
// baseline (166.954 us; speedup 1.0000x reference)
//
#include <hip/hip_runtime.h>
#include <math.h>

// MFMA-based fused autoencoder fwd + Jacobians.
// Per wave: 32 samples. Transposed GEMM formulation per 16-neuron layer:
//   D[i, s] = sum_j W[i,j] * H[j, s]   via  v_mfma_f32_32x32x16_bf16
// A = [W ; 0] (32x16 bf16, prepacked per-lane frags in ws by prep_kernel)
// B = H (16 x 32 samples): lane = (sample = lane&31, half h = lane>>5) holds
//     k = 8h..8h+7  -> layer-1 computes its 8 neurons directly in B-layout.
// C/D layout (verified, m74/m101): col=lane&31, row=(reg&3)+8*(reg>>2)+4*h;
// valid rows 0..15 live in regs 0..7 for every lane (balanced trans work).

typedef float  f32x16 __attribute__((ext_vector_type(16)));
typedef short  bf16x8 __attribute__((ext_vector_type(8)));

__device__ __forceinline__ unsigned short f2bf1(float f) {
    unsigned u = __builtin_bit_cast(unsigned, f);
    u += 0x7FFFu + ((u >> 16) & 1u);          // RNE
    return (unsigned short)(u >> 16);
}

__device__ __forceinline__ unsigned packbf(float a, float b) {
    return (unsigned)f2bf1(a) | ((unsigned)f2bf1(b) << 16);  // a -> low half
}

__device__ __forceinline__ f32x16 zero16() {
    f32x16 z;
#pragma unroll
    for (int r = 0; r < 16; ++r) z[r] = 0.0f;
    return z;
}

__device__ __forceinline__ bf16x8 pack8(const float* v) {
    union { unsigned u[4]; bf16x8 f; } x;
    x.u[0] = packbf(v[0], v[1]); x.u[1] = packbf(v[2], v[3]);
    x.u[2] = packbf(v[4], v[5]); x.u[3] = packbf(v[6], v[7]);
    return x.f;
}

__device__ __forceinline__ void activ(float z, float& sp, float& sg) {
    float e  = __expf(-fabsf(z));             // shared by softplus & sigmoid
    float iv = __builtin_amdgcn_rcpf(1.0f + e);
    sg = (z >= 0.0f) ? iv : e * iv;           // sigmoid(z)
    sp = fmaxf(z, 0.0f) + __logf(1.0f + e);   // stable softplus
}

// C-layout regs v[0..7] (neuron i = (r&3)+8*(r>>2)+4h, sample col = lane&31)
// -> B-frag (lane holds k = 8h..8h+7 of its sample) via one xor-32 exchange.
__device__ __forceinline__ bf16x8 b3frag(const float* v, int h) {
    unsigned P01 = packbf(v[0], v[1]), P23 = packbf(v[2], v[3]);
    unsigned P45 = packbf(v[4], v[5]), P67 = packbf(v[6], v[7]);
    unsigned S0 = h ? P01 : P45;   // send: h=0 gives rows 8-11, h=1 gives rows 4-7
    unsigned S1 = h ? P23 : P67;
    unsigned K0 = h ? P45 : P01;   // keep
    unsigned K1 = h ? P67 : P23;
    unsigned R0 = (unsigned)__shfl_xor((int)S0, 32);
    unsigned R1 = (unsigned)__shfl_xor((int)S1, 32);
    union { unsigned u[4]; bf16x8 f; } x;
    x.u[0] = h ? R0 : K0; x.u[1] = h ? R1 : K1;
    x.u[2] = h ? K0 : R0; x.u[3] = h ? K1 : R1;
    return x.f;
}

// ---- ws layout (float offsets) ----
// encL1 [64][24] @0   decL1 @1536   encB2 [64][8] @3072   decB2 @3584
// bf16 frags @4096 floats: A2e | A3e | A2d | A3d, each 64 lanes x 8 shorts
__global__ void prep_kernel(
    const float* __restrict__ ew1, const float* __restrict__ eb1,
    const float* __restrict__ ew2, const float* __restrict__ eb2,
    const float* __restrict__ ew3,
    const float* __restrict__ dw1, const float* __restrict__ db1,
    const float* __restrict__ dw2, const float* __restrict__ db2,
    const float* __restrict__ dw3,
    float* __restrict__ ws)
{
    const int t = threadIdx.x;
    if (t >= 64) return;
    const int h = t >> 5, m = t & 31;
    unsigned short* frag = (unsigned short*)(ws + 4096);
#pragma unroll
    for (int jj = 0; jj < 8; ++jj) {
        const int j = 8 * h + jj;
        ws[t*24 + jj]             = ew1[2*j];
        ws[t*24 + 8 + jj]         = ew1[2*j + 1];
        ws[t*24 + 16 + jj]        = eb1[j];
        ws[1536 + t*24 + jj]      = dw1[2*j];
        ws[1536 + t*24 + 8 + jj]  = dw1[2*j + 1];
        ws[1536 + t*24 + 16 + jj] = db1[j];
        frag[t*8 + jj]        = (m < 16) ? f2bf1(ew2[m*16 + j]) : (unsigned short)0;
        frag[512 + t*8 + jj]  = (m < 2)  ? f2bf1(ew3[m*16 + j]) : (unsigned short)0;
        frag[1024 + t*8 + jj] = (m < 16) ? f2bf1(dw2[m*16 + j]) : (unsigned short)0;
        frag[1536 + t*8 + jj] = (m < 2)  ? f2bf1(dw3[m*16 + j]) : (unsigned short)0;
    }
#pragma unroll
    for (int r = 0; r < 8; ++r) {
        const int i = (r & 3) + 8 * (r >> 2) + 4 * h;
        ws[3072 + t*8 + r] = eb2[i];
        ws[3584 + t*8 + r] = db2[i];
    }
}

__device__ __forceinline__ void mlp_mfma(
    const float* __restrict__ L1, const float* __restrict__ B2,
    bf16x8 A2, bf16x8 A3, float b30, float b31,
    float x0, float x1, int h,
    float& o0, float& o1, float& J00, float& J01, float& J10, float& J11)
{
    float h1[8], ta[8], tb[8];
#pragma unroll
    for (int jj = 0; jj < 8; ++jj) {
        float wa = L1[jj], wb = L1[8 + jj], bb = L1[16 + jj];
        float z = fmaf(wa, x0, fmaf(wb, x1, bb));
        float sp, sg; activ(z, sp, sg);
        h1[jj] = sp; ta[jj] = sg * wa; tb[jj] = sg * wb;
    }
    bf16x8 Bh = pack8(h1), Bta = pack8(ta), Btb = pack8(tb);
    f32x16 zc = zero16(), ua = zero16(), ub = zero16();
    zc = __builtin_amdgcn_mfma_f32_32x32x16_bf16(A2, Bh,  zc, 0, 0, 0);
    ua = __builtin_amdgcn_mfma_f32_32x32x16_bf16(A2, Bta, ua, 0, 0, 0);
    ub = __builtin_amdgcn_mfma_f32_32x32x16_bf16(A2, Btb, ub, 0, 0, 0);

    float h2[8], sa[8], sb[8];
#pragma unroll
    for (int r = 0; r < 8; ++r) {
        float z = zc[r] + B2[r];
        float sp, sg; activ(z, sp, sg);
        h2[r] = sp; sa[r] = sg * ua[r]; sb[r] = sg * ub[r];
    }
    bf16x8 B3h = b3frag(h2, h), B3a = b3frag(sa, h), B3b = b3frag(sb, h);
    f32x16 oz = zero16(), oa = zero16(), ob = zero16();
    oz = __builtin_amdgcn_mfma_f32_32x32x16_bf16(A3, B3h, oz, 0, 0, 0);
    oa = __builtin_amdgcn_mfma_f32_32x32x16_bf16(A3, B3a, oa, 0, 0, 0);
    ob = __builtin_amdgcn_mfma_f32_32x32x16_bf16(A3, B3b, ob, 0, 0, 0);
    // valid at h==0: reg0 = row0, reg1 = row1
    o0 = oz[0] + b30; o1 = oz[1] + b31;
    J00 = oa[0]; J10 = oa[1]; J01 = ob[0]; J11 = ob[1];
}

__global__ __launch_bounds__(256) void ae_mfma_kernel(
    const float* __restrict__ q,
    const float* __restrict__ eb3, const float* __restrict__ db3,
    const float* __restrict__ ws, float* __restrict__ out, int n)
{
    const int lane = threadIdx.x & 63;
    const int w = blockIdx.x * 4 + (threadIdx.x >> 6);
    const int s32 = lane & 31, h = lane >> 5;
    const long base = (long)w * 32;
    if (base >= n) return;                    // wave-uniform exit
    const int sample = (int)base + s32;
    const int sidx = sample < n ? sample : n - 1;

    const float2 qv = ((const float2*)q)[sidx];
    const float x = qv.x, y = qv.y;

    const float* encL1 = ws + (size_t)lane * 24;
    const float* decL1 = ws + 1536 + (size_t)lane * 24;
    const float* encB2 = ws + 3072 + (size_t)lane * 8;
    const float* decB2 = ws + 3584 + (size_t)lane * 8;
    const bf16x8* fr = (const bf16x8*)(ws + 4096);
    const bf16x8 A2e = fr[lane], A3e = fr[64 + lane];
    const bf16x8 A2d = fr[128 + lane], A3d = fr[192 + lane];
    const float eb30 = eb3[0], eb31 = eb3[1];
    const float db30 = db3[0], db31 = db3[1];

    float eo0, eo1, eJ00, eJ01, eJ10, eJ11;
    mlp_mfma(encL1, encB2, A2e, A3e, eb30, eb31, x, y, h,
             eo0, eo1, eJ00, eJ01, eJ10, eJ11);

    // broadcast theta (valid at h==0, lane s32) to both halves
    const float tx = __shfl(eo0, s32);
    const float ty = __shfl(eo1, s32);

    float qo0, qo1, dJ00, dJ01, dJ10, dJ11;
    mlp_mfma(decL1, decB2, A2d, A3d, db30, db31, tx, ty, h,
             qo0, qo1, dJ00, dJ01, dJ10, dJ11);

    if (h == 0 && sample < n) {
        const float r2   = fmaf(x, x, y * y);
        const float iv   = __builtin_amdgcn_rcpf(r2);
        const float rinv = __builtin_amdgcn_rsqf(r2 + 1e-8f);
        const size_t nn = (size_t)n;
        ((float2*)(out))[sample]           = make_float2(eo0, eo1);
        ((float4*)(out + 2 * nn))[sample]  = make_float4(eJ00, eJ01, eJ10, eJ11);
        ((float2*)(out + 6 * nn))[sample]  = make_float2(qo0, qo1);
        ((float4*)(out + 8 * nn))[sample]  = make_float4(dJ00, dJ01, dJ10, dJ11);
        ((float4*)(out + 12 * nn))[sample] = make_float4(-y * iv, x * iv, x * rinv, y * rinv);
    }
}

extern "C" void kernel_launch(void* const* d_in, const int* in_sizes, int n_in,
                              void* d_out, int out_size, void* d_ws, size_t ws_size,
                              hipStream_t stream)
{
    const float* q   = (const float*)d_in[0];
    const float* ew1 = (const float*)d_in[1];
    const float* eb1 = (const float*)d_in[2];
    const float* ew2 = (const float*)d_in[3];
    const float* eb2 = (const float*)d_in[4];
    const float* ew3 = (const float*)d_in[5];
    const float* eb3 = (const float*)d_in[6];
    const float* dw1 = (const float*)d_in[7];
    const float* db1 = (const float*)d_in[8];
    const float* dw2 = (const float*)d_in[9];
    const float* db2 = (const float*)d_in[10];
    const float* dw3 = (const float*)d_in[11];
    const float* db3 = (const float*)d_in[12];

    const int n = in_sizes[0] / 2;
    float* ws = (float*)d_ws;

    prep_kernel<<<1, 64, 0, stream>>>(ew1, eb1, ew2, eb2, ew3,
                                      dw1, db1, dw2, db2, dw3, ws);

    const int waves  = (n + 31) / 32;
    const int blocks = (waves + 3) / 4;
    ae_mfma_kernel<<<blocks, 256, 0, stream>>>(q, eb3, db3, ws, (float*)d_out, n);
}

// Round 5
// 156.278 us; speedup vs baseline: 1.0683x; 1.0683x over previous
//
#include <hip/hip_runtime.h>
#include <math.h>

// MFMA-based fused autoencoder fwd + Jacobians.
// Per wave: 64 samples (two 32-sample groups). Transposed GEMM per layer:
//   D[i, s] = sum_j W[i,j] * H[j, s]   via  v_mfma_f32_32x32x16_bf16
// A = [W ; 0] (32x16 bf16, prepacked per-lane frags in ws by prep_kernel)
// B = H (16 x 32 samples): lane = (sample = lane&31, half h = lane>>5) holds
//     k = 8h..8h+7  -> layer-1 computes its 8 neurons directly in B-layout.
// C/D layout (verified, m74/m101): col=lane&31, row=(reg&3)+8*(reg>>2)+4*h.
// Dynamic float->bf16 packs use single v_perm_b32 (truncation) -- threshold
// is bf16-floor (7.72 vs our ~0.3), RNE sequence (~9 inst) not needed.

typedef float  f32x16 __attribute__((ext_vector_type(16)));
typedef short  bf16x8 __attribute__((ext_vector_type(8)));

__device__ __forceinline__ unsigned short f2bf1(float f) {   // RNE (prep only)
    unsigned u = __builtin_bit_cast(unsigned, f);
    u += 0x7FFFu + ((u >> 16) & 1u);
    return (unsigned short)(u >> 16);
}

// packed truncating f32->bf16 pair: 1 x v_perm_b32 (a -> low half)
__device__ __forceinline__ unsigned packbf(float a, float b) {
    return __builtin_amdgcn_perm(__builtin_bit_cast(unsigned, b),
                                 __builtin_bit_cast(unsigned, a), 0x07060302u);
}

__device__ __forceinline__ f32x16 zero16() {
    f32x16 z;
#pragma unroll
    for (int r = 0; r < 16; ++r) z[r] = 0.0f;
    return z;
}

__device__ __forceinline__ bf16x8 pack8(const float* v) {
    union { unsigned u[4]; bf16x8 f; } x;
    x.u[0] = packbf(v[0], v[1]); x.u[1] = packbf(v[2], v[3]);
    x.u[2] = packbf(v[4], v[5]); x.u[3] = packbf(v[6], v[7]);
    return x.f;
}

__device__ __forceinline__ void activ(float z, float& sp, float& sg) {
    float e  = __expf(-fabsf(z));             // shared by softplus & sigmoid
    float iv = __builtin_amdgcn_rcpf(1.0f + e);
    sg = (z >= 0.0f) ? iv : e * iv;           // sigmoid(z)
    sp = fmaxf(z, 0.0f) + __logf(1.0f + e);   // stable softplus
}

// C-layout regs v[0..7] (neuron i = (r&3)+8*(r>>2)+4h, sample col = lane&31)
// -> B-frag (lane holds k = 8h..8h+7 of its sample) via one xor-32 exchange.
__device__ __forceinline__ bf16x8 b3frag(const float* v, int h) {
    unsigned P01 = packbf(v[0], v[1]), P23 = packbf(v[2], v[3]);
    unsigned P45 = packbf(v[4], v[5]), P67 = packbf(v[6], v[7]);
    unsigned S0 = h ? P01 : P45;   // send: h=0 gives rows 8-11, h=1 gives rows 4-7
    unsigned S1 = h ? P23 : P67;
    unsigned K0 = h ? P45 : P01;   // keep
    unsigned K1 = h ? P67 : P23;
    unsigned R0 = (unsigned)__shfl_xor((int)S0, 32);
    unsigned R1 = (unsigned)__shfl_xor((int)S1, 32);
    union { unsigned u[4]; bf16x8 f; } x;
    x.u[0] = h ? R0 : K0; x.u[1] = h ? R1 : K1;
    x.u[2] = h ? K0 : R0; x.u[3] = h ? K1 : R1;
    return x.f;
}

// ---- ws layout (float offsets) ----
// encL1 [64][24] @0   decL1 @1536   encB2 [64][8] @3072   decB2 @3584
// bf16 frags @4096 floats: A2e | A3e | A2d | A3d, each 64 lanes x 8 shorts
__global__ void prep_kernel(
    const float* __restrict__ ew1, const float* __restrict__ eb1,
    const float* __restrict__ ew2, const float* __restrict__ eb2,
    const float* __restrict__ ew3,
    const float* __restrict__ dw1, const float* __restrict__ db1,
    const float* __restrict__ dw2, const float* __restrict__ db2,
    const float* __restrict__ dw3,
    float* __restrict__ ws)
{
    const int t = threadIdx.x;
    if (t >= 64) return;
    const int h = t >> 5, m = t & 31;
    unsigned short* frag = (unsigned short*)(ws + 4096);
#pragma unroll
    for (int jj = 0; jj < 8; ++jj) {
        const int j = 8 * h + jj;
        ws[t*24 + jj]             = ew1[2*j];
        ws[t*24 + 8 + jj]         = ew1[2*j + 1];
        ws[t*24 + 16 + jj]        = eb1[j];
        ws[1536 + t*24 + jj]      = dw1[2*j];
        ws[1536 + t*24 + 8 + jj]  = dw1[2*j + 1];
        ws[1536 + t*24 + 16 + jj] = db1[j];
        frag[t*8 + jj]        = (m < 16) ? f2bf1(ew2[m*16 + j]) : (unsigned short)0;
        frag[512 + t*8 + jj]  = (m < 2)  ? f2bf1(ew3[m*16 + j]) : (unsigned short)0;
        frag[1024 + t*8 + jj] = (m < 16) ? f2bf1(dw2[m*16 + j]) : (unsigned short)0;
        frag[1536 + t*8 + jj] = (m < 2)  ? f2bf1(dw3[m*16 + j]) : (unsigned short)0;
    }
#pragma unroll
    for (int r = 0; r < 8; ++r) {
        const int i = (r & 3) + 8 * (r >> 2) + 4 * h;
        ws[3072 + t*8 + r] = eb2[i];
        ws[3584 + t*8 + r] = db2[i];
    }
}

__device__ __forceinline__ void mlp_mfma(
    const float* __restrict__ L1, const float* __restrict__ B2,
    bf16x8 A2, bf16x8 A3, float b30, float b31,
    float x0, float x1, int h,
    float& o0, float& o1, float& J00, float& J01, float& J10, float& J11)
{
    float h1[8], ta[8], tb[8];
#pragma unroll
    for (int jj = 0; jj < 8; ++jj) {
        float wa = L1[jj], wb = L1[8 + jj], bb = L1[16 + jj];
        float z = fmaf(wa, x0, fmaf(wb, x1, bb));
        float sp, sg; activ(z, sp, sg);
        h1[jj] = sp; ta[jj] = sg * wa; tb[jj] = sg * wb;
    }
    bf16x8 Bh = pack8(h1), Bta = pack8(ta), Btb = pack8(tb);
    f32x16 zc = zero16(), ua = zero16(), ub = zero16();
    zc = __builtin_amdgcn_mfma_f32_32x32x16_bf16(A2, Bh,  zc, 0, 0, 0);
    ua = __builtin_amdgcn_mfma_f32_32x32x16_bf16(A2, Bta, ua, 0, 0, 0);
    ub = __builtin_amdgcn_mfma_f32_32x32x16_bf16(A2, Btb, ub, 0, 0, 0);

    float h2[8], sa[8], sb[8];
#pragma unroll
    for (int r = 0; r < 8; ++r) {
        float z = zc[r] + B2[r];
        float sp, sg; activ(z, sp, sg);
        h2[r] = sp; sa[r] = sg * ua[r]; sb[r] = sg * ub[r];
    }
    bf16x8 B3h = b3frag(h2, h), B3a = b3frag(sa, h), B3b = b3frag(sb, h);
    f32x16 oz = zero16(), oa = zero16(), ob = zero16();
    oz = __builtin_amdgcn_mfma_f32_32x32x16_bf16(A3, B3h, oz, 0, 0, 0);
    oa = __builtin_amdgcn_mfma_f32_32x32x16_bf16(A3, B3a, oa, 0, 0, 0);
    ob = __builtin_amdgcn_mfma_f32_32x32x16_bf16(A3, B3b, ob, 0, 0, 0);
    // valid at h==0: reg0 = row0, reg1 = row1
    o0 = oz[0] + b30; o1 = oz[1] + b31;
    J00 = oa[0]; J10 = oa[1]; J01 = ob[0]; J11 = ob[1];
}

__device__ __forceinline__ void do_group(
    const float* __restrict__ q, float* __restrict__ out, int n, int sbase,
    int s32, int h,
    const float* __restrict__ encL1, const float* __restrict__ decL1,
    const float* __restrict__ encB2, const float* __restrict__ decB2,
    bf16x8 A2e, bf16x8 A3e, bf16x8 A2d, bf16x8 A3d,
    float eb30, float eb31, float db30, float db31)
{
    const int sample = sbase + s32;
    const int sidx = sample < n ? sample : n - 1;

    const float2 qv = ((const float2*)q)[sidx];
    const float x = qv.x, y = qv.y;

    float eo0, eo1, eJ00, eJ01, eJ10, eJ11;
    mlp_mfma(encL1, encB2, A2e, A3e, eb30, eb31, x, y, h,
             eo0, eo1, eJ00, eJ01, eJ10, eJ11);

    // broadcast theta (valid at h==0, lane s32) to both halves
    const float tx = __shfl(eo0, s32);
    const float ty = __shfl(eo1, s32);

    float qo0, qo1, dJ00, dJ01, dJ10, dJ11;
    mlp_mfma(decL1, decB2, A2d, A3d, db30, db31, tx, ty, h,
             qo0, qo1, dJ00, dJ01, dJ10, dJ11);

    if (h == 0 && sample < n) {
        const float r2   = fmaf(x, x, y * y);
        const float iv   = __builtin_amdgcn_rcpf(r2);
        const float rinv = __builtin_amdgcn_rsqf(r2 + 1e-8f);
        const size_t nn = (size_t)n;
        ((float2*)(out))[sample]           = make_float2(eo0, eo1);
        ((float4*)(out + 2 * nn))[sample]  = make_float4(eJ00, eJ01, eJ10, eJ11);
        ((float2*)(out + 6 * nn))[sample]  = make_float2(qo0, qo1);
        ((float4*)(out + 8 * nn))[sample]  = make_float4(dJ00, dJ01, dJ10, dJ11);
        ((float4*)(out + 12 * nn))[sample] = make_float4(-y * iv, x * iv, x * rinv, y * rinv);
    }
}

__global__ __launch_bounds__(256) void ae_mfma_kernel(
    const float* __restrict__ q,
    const float* __restrict__ eb3, const float* __restrict__ db3,
    const float* __restrict__ ws, float* __restrict__ out, int n)
{
    const int lane = threadIdx.x & 63;
    const int w = blockIdx.x * 4 + (threadIdx.x >> 6);
    const int s32 = lane & 31, h = lane >> 5;
    const long base = (long)w * 64;            // 64 samples per wave
    if (base >= n) return;                     // wave-uniform exit

    const float* encL1 = ws + (size_t)lane * 24;
    const float* decL1 = ws + 1536 + (size_t)lane * 24;
    const float* encB2 = ws + 3072 + (size_t)lane * 8;
    const float* decB2 = ws + 3584 + (size_t)lane * 8;
    const bf16x8* fr = (const bf16x8*)(ws + 4096);
    const bf16x8 A2e = fr[lane], A3e = fr[64 + lane];
    const bf16x8 A2d = fr[128 + lane], A3d = fr[192 + lane];
    const float eb30 = eb3[0], eb31 = eb3[1];
    const float db30 = db3[0], db31 = db3[1];

    do_group(q, out, n, (int)base, s32, h, encL1, decL1, encB2, decB2,
             A2e, A3e, A2d, A3d, eb30, eb31, db30, db31);
    if (base + 32 < n)
        do_group(q, out, n, (int)base + 32, s32, h, encL1, decL1, encB2, decB2,
                 A2e, A3e, A2d, A3d, eb30, eb31, db30, db31);
}

extern "C" void kernel_launch(void* const* d_in, const int* in_sizes, int n_in,
                              void* d_out, int out_size, void* d_ws, size_t ws_size,
                              hipStream_t stream)
{
    const float* q   = (const float*)d_in[0];
    const float* ew1 = (const float*)d_in[1];
    const float* eb1 = (const float*)d_in[2];
    const float* ew2 = (const float*)d_in[3];
    const float* eb2 = (const float*)d_in[4];
    const float* ew3 = (const float*)d_in[5];
    const float* eb3 = (const float*)d_in[6];
    const float* dw1 = (const float*)d_in[7];
    const float* db1 = (const float*)d_in[8];
    const float* dw2 = (const float*)d_in[9];
    const float* db2 = (const float*)d_in[10];
    const float* dw3 = (const float*)d_in[11];
    const float* db3 = (const float*)d_in[12];

    const int n = in_sizes[0] / 2;
    float* ws = (float*)d_ws;

    prep_kernel<<<1, 64, 0, stream>>>(ew1, eb1, ew2, eb2, ew3,
                                      dw1, db1, dw2, db2, dw3, ws);

    const int waves  = (n + 63) / 64;
    const int blocks = (waves + 3) / 4;
    ae_mfma_kernel<<<blocks, 256, 0, stream>>>(q, eb3, db3, ws, (float*)d_out, n);
}